// Round 12
// baseline (309.248 us; speedup 1.0000x reference)
//
#include <hip/hip_runtime.h>
#include <hip/hip_bf16.h>

#define NN 50000
#define NE 1000000
#define DIM 64
#define NG 256
#define NBUCK 196        // ceil(NN/256) buckets of 256 dst nodes
#define ROUND 4096       // edges per block in hist2d/permute
#define NBLK 245         // ceil(NE/ROUND)
#define TOT2D (NBUCK * NBLK)   // 48020
#define SCANB 47         // ceil(TOT2D/1024)

// ---- pass 1: per-block bucket histogram -> hist[b*NBLK + blk]; also zeros pool ----
__global__ __launch_bounds__(512) void hist2d_kernel(const int* __restrict__ dst,
                                                     int* __restrict__ hist,
                                                     float* __restrict__ pool) {
    int gtid = blockIdx.x * 512 + threadIdx.x;
    for (int i = gtid; i < 3 * NG * DIM; i += NBLK * 512) pool[i] = 0.f;

    __shared__ int h[NBUCK];
    int t = threadIdx.x;
    if (t < NBUCK) h[t] = 0;
    __syncthreads();
    int base = blockIdx.x * ROUND;
#pragma unroll
    for (int it = 0; it < 8; ++it) {
        int e = base + it * 512 + t;
        if (e < NE) atomicAdd(&h[dst[e] >> 8], 1);
    }
    __syncthreads();
    if (t < NBUCK) hist[t * NBLK + blockIdx.x] = h[t];
}

// ---- pass 2: flat exclusive scan of hist[TOT2D] ----
__global__ __launch_bounds__(1024) void scanA_kernel(const int* __restrict__ hist,
                                                     int* __restrict__ blocksum) {
    __shared__ int tmp[1024];
    int t = threadIdx.x;
    int i = blockIdx.x * 1024 + t;
    tmp[t] = (i < TOT2D) ? hist[i] : 0;
    __syncthreads();
    for (int s = 512; s > 0; s >>= 1) {
        if (t < s) tmp[t] += tmp[t + s];
        __syncthreads();
    }
    if (t == 0) blocksum[blockIdx.x] = tmp[0];
}

__global__ __launch_bounds__(64) void scanB_kernel(int* __restrict__ blocksum) {
    __shared__ int tmp[64];
    int t = threadIdx.x;
    int v = (t < SCANB) ? blocksum[t] : 0;
    tmp[t] = v;
    __syncthreads();
    for (int off = 1; off < 64; off <<= 1) {
        int a = (t >= off) ? tmp[t - off] : 0;
        __syncthreads();
        tmp[t] += a;
        __syncthreads();
    }
    if (t < SCANB) blocksum[t] = tmp[t] - v;   // exclusive
}

__global__ __launch_bounds__(1024) void scanC_kernel(const int* __restrict__ hist,
                                                     const int* __restrict__ blocksum,
                                                     int* __restrict__ scanned) {
    __shared__ int tmp[1024];
    int t = threadIdx.x;
    int i = blockIdx.x * 1024 + t;
    int v = (i < TOT2D) ? hist[i] : 0;
    tmp[t] = v;
    __syncthreads();
    for (int off = 1; off < 1024; off <<= 1) {
        int a = (t >= off) ? tmp[t - off] : 0;
        __syncthreads();
        tmp[t] += a;
        __syncthreads();
    }
    if (i < TOT2D) scanned[i] = tmp[t] - v + blocksum[blockIdx.x];
}

// ---- pass 3: permute edges into bucket-major order (no global atomics) ----
__global__ __launch_bounds__(512) void permute_kernel(
    const int* __restrict__ src, const int* __restrict__ dst,
    const int* __restrict__ scanned, unsigned int* __restrict__ bucketed) {
    __shared__ int cur[NBUCK];
    int t = threadIdx.x;
    int blk = blockIdx.x;
    if (t < NBUCK) cur[t] = scanned[t * NBLK + blk];
    __syncthreads();
    int base = blk * ROUND;
#pragma unroll
    for (int it = 0; it < 8; ++it) {
        int e = base + it * 512 + t;
        if (e < NE) {
            int d = dst[e];
            int s = src[e];
            int b = d >> 8;
            int pos = atomicAdd(&cur[b], 1);
            bucketed[pos] = ((unsigned int)(d & 255) << 16) | (unsigned int)s;
        }
    }
}

// ---- pass 4: per-bucket counting sort -> exact CSR ----
__global__ __launch_bounds__(512) void bucket_sort_kernel(
    const unsigned int* __restrict__ bucketed, const int* __restrict__ scanned,
    int* __restrict__ offsets, int* __restrict__ csr) {
    __shared__ int hist[256];
    __shared__ int sc[256];
    __shared__ int cur[256];
    int b = blockIdx.x;
    int t = threadIdx.x;
    if (t < 256) hist[t] = 0;
    __syncthreads();
    int gbase = scanned[b * NBLK];
    int gend  = (b < NBUCK - 1) ? scanned[(b + 1) * NBLK] : NE;
    int count = gend - gbase;
    const unsigned int* bd = bucketed + gbase;
    for (int e = t; e < count; e += 512) atomicAdd(&hist[bd[e] >> 16], 1);
    __syncthreads();
    if (t < 256) sc[t] = hist[t];
    __syncthreads();
    for (int off = 1; off < 256; off <<= 1) {
        int a = 0;
        if (t < 256 && t >= off) a = sc[t - off];
        __syncthreads();
        if (t < 256) sc[t] += a;
        __syncthreads();
    }
    if (t < 256) {
        int excl = sc[t] - hist[t];
        cur[t] = excl;
        int node = b * 256 + t;
        if (node < NN) offsets[node] = gbase + excl;
    }
    if (b == NBUCK - 1 && t == 0) offsets[NN] = NE;
    __syncthreads();
    for (int e = t; e < count; e += 512) {
        unsigned int v = bd[e];
        int p = atomicAdd(&cur[v >> 16], 1);
        csr[gbase + p] = (int)(v & 0xFFFFu);
    }
}

// ---------- H = X @ W -> bf16 : thread-per-row, W wave-uniform (s_load) ----------
__global__ __launch_bounds__(128) void gemm64_kernel(const float* __restrict__ X,
                                                     const float* __restrict__ W,
                                                     __hip_bfloat16* __restrict__ H,
                                                     int nrows) {
    __shared__ float Xl[128 * 65];   // +1 pad
    int t = threadIdx.x;
    int base = blockIdx.x * 128;
    for (int idx = t; idx < 128 * 16; idx += 128) {
        int row = idx >> 4;
        int c4  = idx & 15;
        float4 v = make_float4(0.f, 0.f, 0.f, 0.f);
        if (base + row < nrows)
            v = *reinterpret_cast<const float4*>(&X[(size_t)(base + row) * 64 + c4 * 4]);
        float* p = &Xl[row * 65 + c4 * 4];
        p[0] = v.x; p[1] = v.y; p[2] = v.z; p[3] = v.w;
    }
    __syncthreads();
    float acc[64];
#pragma unroll
    for (int c = 0; c < 64; ++c) acc[c] = 0.f;
#pragma unroll 4
    for (int k = 0; k < 64; ++k) {
        float xv = Xl[t * 65 + k];
#pragma unroll
        for (int c4 = 0; c4 < 16; ++c4) {
            float4 w = *reinterpret_cast<const float4*>(&W[k * 64 + c4 * 4]); // uniform -> s_load
            acc[c4 * 4 + 0] = fmaf(xv, w.x, acc[c4 * 4 + 0]);
            acc[c4 * 4 + 1] = fmaf(xv, w.y, acc[c4 * 4 + 1]);
            acc[c4 * 4 + 2] = fmaf(xv, w.z, acc[c4 * 4 + 2]);
            acc[c4 * 4 + 3] = fmaf(xv, w.w, acc[c4 * 4 + 3]);
        }
    }
    int row = base + t;
    if (row < nrows) {
        alignas(16) __hip_bfloat16 hb[64];
#pragma unroll
        for (int c = 0; c < 64; ++c) hb[c] = __float2bfloat16(acc[c]);
        uint4* dst4 = reinterpret_cast<uint4*>(&H[(size_t)row * 64]);
        const uint4* src4 = reinterpret_cast<const uint4*>(hb);
#pragma unroll
        for (int q = 0; q < 8; ++q) dst4[q] = src4[q];
    }
}

// bf16x2 unpack-accumulate from one uint32
#define ACC2(u, alo, ahi)                                           \
    alo += __uint_as_float((u) << 16);                              \
    ahi += __uint_as_float((u) & 0xffff0000u);

// ---------- gather: 8 lanes x 16B per edge-row -> 8 edges per wave-load ----------
// lane = egrp*8 + cpart: egrp = edge slot (0..7), cpart = 8-col chunk (0..7)
template <bool WRITE_X>
__global__ void gather_kernel(const __hip_bfloat16* __restrict__ H,
                              const int* __restrict__ offsets,
                              const int* __restrict__ csr, const int* __restrict__ batch,
                              float* __restrict__ Xout, float* __restrict__ pool) {
    int tid = blockIdx.x * blockDim.x + threadIdx.x;
    int lane = tid & 63;
    int egrp = lane >> 3;
    int cpart = lane & 7;
    int gw = tid >> 6;
    int nw = (gridDim.x * blockDim.x) >> 6;
    int chunk = (NN + nw - 1) / nw;           // contiguous nodes per wave
    int start = gw * chunk;
    if (start >= NN) return;
    int stop = min(start + chunk, NN);
    float p0 = 0.f, p1 = 0.f, p2 = 0.f, p3 = 0.f, p4 = 0.f, p5 = 0.f, p6 = 0.f, p7 = 0.f;
    int curg = batch[start];
    for (int n = start; n < stop; ++n) {
        int beg = offsets[n], end = offsets[n + 1];
        float a0 = 0.f, a1 = 0.f, a2 = 0.f, a3 = 0.f;
        float a4 = 0.f, a5 = 0.f, a6 = 0.f, a7 = 0.f;
        for (int e0 = beg; e0 < end; e0 += 32) {    // 32 edges per batch, 4 loads in flight
            uint4 h0 = make_uint4(0, 0, 0, 0), h1 = h0, h2 = h0, h3 = h0;
            int e;
            e = e0 + egrp;
            if (e < end) h0 = *reinterpret_cast<const uint4*>(&H[(size_t)csr[e] * 64 + cpart * 8]);
            e = e0 + 8 + egrp;
            if (e < end) h1 = *reinterpret_cast<const uint4*>(&H[(size_t)csr[e] * 64 + cpart * 8]);
            e = e0 + 16 + egrp;
            if (e < end) h2 = *reinterpret_cast<const uint4*>(&H[(size_t)csr[e] * 64 + cpart * 8]);
            e = e0 + 24 + egrp;
            if (e < end) h3 = *reinterpret_cast<const uint4*>(&H[(size_t)csr[e] * 64 + cpart * 8]);
            ACC2(h0.x, a0, a1) ACC2(h0.y, a2, a3) ACC2(h0.z, a4, a5) ACC2(h0.w, a6, a7)
            ACC2(h1.x, a0, a1) ACC2(h1.y, a2, a3) ACC2(h1.z, a4, a5) ACC2(h1.w, a6, a7)
            ACC2(h2.x, a0, a1) ACC2(h2.y, a2, a3) ACC2(h2.z, a4, a5) ACC2(h2.w, a6, a7)
            ACC2(h3.x, a0, a1) ACC2(h3.y, a2, a3) ACC2(h3.z, a4, a5) ACC2(h3.w, a6, a7)
        }
        // reduce across the 8 edge slots (lane bits 3..5)
#pragma unroll
        for (int m = 8; m <= 32; m <<= 1) {
            a0 += __shfl_xor(a0, m, 64); a1 += __shfl_xor(a1, m, 64);
            a2 += __shfl_xor(a2, m, 64); a3 += __shfl_xor(a3, m, 64);
            a4 += __shfl_xor(a4, m, 64); a5 += __shfl_xor(a5, m, 64);
            a6 += __shfl_xor(a6, m, 64); a7 += __shfl_xor(a7, m, 64);
        }
        float v0 = fmaxf(a0, 0.f), v1 = fmaxf(a1, 0.f), v2 = fmaxf(a2, 0.f), v3 = fmaxf(a3, 0.f);
        float v4 = fmaxf(a4, 0.f), v5 = fmaxf(a5, 0.f), v6 = fmaxf(a6, 0.f), v7 = fmaxf(a7, 0.f);
        if (WRITE_X && egrp == 0) {
            float4* o = reinterpret_cast<float4*>(&Xout[(size_t)n * 64 + cpart * 8]);
            o[0] = make_float4(v0, v1, v2, v3);
            o[1] = make_float4(v4, v5, v6, v7);
        }
        int g = batch[n];                          // wave-uniform (batch sorted)
        if (g != curg) {
            if (egrp == 0) {
                float* pp = &pool[(size_t)curg * 64 + cpart * 8];
                unsafeAtomicAdd(pp + 0, p0); unsafeAtomicAdd(pp + 1, p1);
                unsafeAtomicAdd(pp + 2, p2); unsafeAtomicAdd(pp + 3, p3);
                unsafeAtomicAdd(pp + 4, p4); unsafeAtomicAdd(pp + 5, p5);
                unsafeAtomicAdd(pp + 6, p6); unsafeAtomicAdd(pp + 7, p7);
            }
            p0 = p1 = p2 = p3 = p4 = p5 = p6 = p7 = 0.f;
            curg = g;
        }
        p0 += v0; p1 += v1; p2 += v2; p3 += v3;
        p4 += v4; p5 += v5; p6 += v6; p7 += v7;
    }
    if (egrp == 0) {
        float* pp = &pool[(size_t)curg * 64 + cpart * 8];
        unsafeAtomicAdd(pp + 0, p0); unsafeAtomicAdd(pp + 1, p1);
        unsafeAtomicAdd(pp + 2, p2); unsafeAtomicAdd(pp + 3, p3);
        unsafeAtomicAdd(pp + 4, p4); unsafeAtomicAdd(pp + 5, p5);
        unsafeAtomicAdd(pp + 6, p6); unsafeAtomicAdd(pp + 7, p7);
    }
}

// ---------- out[g] = relu(sum_l pool_l[g] @ Wp_l) ----------
__global__ void final_kernel(const float* __restrict__ P1, const float* __restrict__ P2,
                             const float* __restrict__ P3,
                             const float* __restrict__ Wp1, const float* __restrict__ Wp2,
                             const float* __restrict__ Wp3, float* __restrict__ out) {
    int g = blockIdx.x;
    int c = threadIdx.x;  // 64
    float acc = 0.f;
#pragma unroll
    for (int k = 0; k < 64; ++k) {
        acc = fmaf(P1[g * 64 + k], Wp1[k * 64 + c], acc);
        acc = fmaf(P2[g * 64 + k], Wp2[k * 64 + c], acc);
        acc = fmaf(P3[g * 64 + k], Wp3[k * 64 + c], acc);
    }
    out[g * 64 + c] = fmaxf(acc, 0.f);
}

extern "C" void kernel_launch(void* const* d_in, const int* in_sizes, int n_in,
                              void* d_out, int out_size, void* d_ws, size_t ws_size,
                              hipStream_t stream) {
    const float* x     = (const float*)d_in[0];
    const int*   eidx  = (const int*)d_in[1];   // [2, NE]
    const int*   batch = (const int*)d_in[2];   // [NN], sorted
    const float* W1  = (const float*)d_in[3];
    const float* W2  = (const float*)d_in[4];
    const float* W3  = (const float*)d_in[5];
    const float* Wp1 = (const float*)d_in[6];
    const float* Wp2 = (const float*)d_in[7];
    const float* Wp3 = (const float*)d_in[8];
    float* out = (float*)d_out;

    const int* src = eidx;
    const int* dst = eidx + NE;

    // ---- workspace layout (~28 MB) ----
    __hip_bfloat16* bufH = (__hip_bfloat16*)d_ws;        // H bf16 (6.4 MB)
    float* bufX  = (float*)(bufH + (size_t)NN * DIM);    // x_l fp32 (12.8 MB)
    float* pool1 = bufX + (size_t)NN * DIM;              // 3 x 64 KB
    float* pool2 = pool1 + (size_t)NG * DIM;
    float* pool3 = pool2 + (size_t)NG * DIM;
    int* hist     = (int*)(pool3 + (size_t)NG * DIM);    // TOT2D
    int* scanned  = hist + TOT2D;                        // TOT2D
    int* blocksum = scanned + TOT2D;                     // 64
    int* offsets  = blocksum + 64;                       // NN+1
    unsigned int* bucketed = (unsigned int*)(offsets + NN + 1);  // NE (4 MB)
    int* csr      = (int*)(bucketed + NE);               // NE (4 MB)

    // ---- build exact CSR: hist(+pool zero) -> scan -> permute -> bucket sort ----
    hist2d_kernel<<<NBLK, 512, 0, stream>>>(dst, hist, pool1);
    scanA_kernel<<<SCANB, 1024, 0, stream>>>(hist, blocksum);
    scanB_kernel<<<1, 64, 0, stream>>>(blocksum);
    scanC_kernel<<<SCANB, 1024, 0, stream>>>(hist, blocksum, scanned);
    permute_kernel<<<NBLK, 512, 0, stream>>>(src, dst, scanned, bucketed);
    bucket_sort_kernel<<<NBUCK, 512, 0, stream>>>(bucketed, scanned, offsets, csr);

    const int gemm_blocks = (NN + 127) / 128;           // 391
    const int gath_blocks = 1792;                        // 7168 waves, 7 nodes each

    // layer 1
    gemm64_kernel<<<gemm_blocks, 128, 0, stream>>>(x, W1, bufH, NN);
    gather_kernel<true><<<gath_blocks, 256, 0, stream>>>(bufH, offsets, csr, batch, bufX, pool1);
    // layer 2
    gemm64_kernel<<<gemm_blocks, 128, 0, stream>>>(bufX, W2, bufH, NN);
    gather_kernel<true><<<gath_blocks, 256, 0, stream>>>(bufH, offsets, csr, batch, bufX, pool2);
    // layer 3 (x3 only feeds the pool -> skip Xout write)
    gemm64_kernel<<<gemm_blocks, 128, 0, stream>>>(bufX, W3, bufH, NN);
    gather_kernel<false><<<gath_blocks, 256, 0, stream>>>(bufH, offsets, csr, batch, nullptr, pool3);

    final_kernel<<<NG, 64, 0, stream>>>(pool1, pool2, pool3, Wp1, Wp2, Wp3, out);
}

// Round 14
// 307.832 us; speedup vs baseline: 1.0046x; 1.0046x over previous
//
#include <hip/hip_runtime.h>
#include <hip/hip_bf16.h>

#define NN 50000
#define NE 1000000
#define DIM 64
#define NG 256
#define NBUCK 196        // ceil(NN/256) buckets of 256 dst nodes
#define ROUND 4096       // edges per block in hist2d/permute
#define NBLK 245         // ceil(NE/ROUND)
#define TOT2D (NBUCK * NBLK)   // 48020
#define SCANB 47         // ceil(TOT2D/1024)

// ---- pass 1: per-block bucket histogram -> hist[b*NBLK + blk]; also zeros pool ----
__global__ __launch_bounds__(512) void hist2d_kernel(const int* __restrict__ dst,
                                                     int* __restrict__ hist,
                                                     float* __restrict__ pool) {
    int gtid = blockIdx.x * 512 + threadIdx.x;
    for (int i = gtid; i < 3 * NG * DIM; i += NBLK * 512) pool[i] = 0.f;

    __shared__ int h[NBUCK];
    int t = threadIdx.x;
    if (t < NBUCK) h[t] = 0;
    __syncthreads();
    int base = blockIdx.x * ROUND;
#pragma unroll
    for (int it = 0; it < 8; ++it) {
        int e = base + it * 512 + t;
        if (e < NE) atomicAdd(&h[dst[e] >> 8], 1);
    }
    __syncthreads();
    if (t < NBUCK) hist[t * NBLK + blockIdx.x] = h[t];
}

// ---- pass 2: flat exclusive scan of hist[TOT2D] ----
__global__ __launch_bounds__(1024) void scanA_kernel(const int* __restrict__ hist,
                                                     int* __restrict__ blocksum) {
    __shared__ int tmp[1024];
    int t = threadIdx.x;
    int i = blockIdx.x * 1024 + t;
    tmp[t] = (i < TOT2D) ? hist[i] : 0;
    __syncthreads();
    for (int s = 512; s > 0; s >>= 1) {
        if (t < s) tmp[t] += tmp[t + s];
        __syncthreads();
    }
    if (t == 0) blocksum[blockIdx.x] = tmp[0];
}

__global__ __launch_bounds__(64) void scanB_kernel(int* __restrict__ blocksum) {
    __shared__ int tmp[64];
    int t = threadIdx.x;
    int v = (t < SCANB) ? blocksum[t] : 0;
    tmp[t] = v;
    __syncthreads();
    for (int off = 1; off < 64; off <<= 1) {
        int a = (t >= off) ? tmp[t - off] : 0;
        __syncthreads();
        tmp[t] += a;
        __syncthreads();
    }
    if (t < SCANB) blocksum[t] = tmp[t] - v;   // exclusive
}

__global__ __launch_bounds__(1024) void scanC_kernel(const int* __restrict__ hist,
                                                     const int* __restrict__ blocksum,
                                                     int* __restrict__ scanned) {
    __shared__ int tmp[1024];
    int t = threadIdx.x;
    int i = blockIdx.x * 1024 + t;
    int v = (i < TOT2D) ? hist[i] : 0;
    tmp[t] = v;
    __syncthreads();
    for (int off = 1; off < 1024; off <<= 1) {
        int a = (t >= off) ? tmp[t - off] : 0;
        __syncthreads();
        tmp[t] += a;
        __syncthreads();
    }
    if (i < TOT2D) scanned[i] = tmp[t] - v + blocksum[blockIdx.x];
}

// ---- pass 3: permute edges into bucket-major order (no global atomics) ----
__global__ __launch_bounds__(512) void permute_kernel(
    const int* __restrict__ src, const int* __restrict__ dst,
    const int* __restrict__ scanned, unsigned int* __restrict__ bucketed) {
    __shared__ int cur[NBUCK];
    int t = threadIdx.x;
    int blk = blockIdx.x;
    if (t < NBUCK) cur[t] = scanned[t * NBLK + blk];
    __syncthreads();
    int base = blk * ROUND;
#pragma unroll
    for (int it = 0; it < 8; ++it) {
        int e = base + it * 512 + t;
        if (e < NE) {
            int d = dst[e];
            int s = src[e];
            int b = d >> 8;
            int pos = atomicAdd(&cur[b], 1);
            bucketed[pos] = ((unsigned int)(d & 255) << 16) | (unsigned int)s;
        }
    }
}

// ---- pass 4: per-bucket counting sort -> exact CSR ----
__global__ __launch_bounds__(512) void bucket_sort_kernel(
    const unsigned int* __restrict__ bucketed, const int* __restrict__ scanned,
    int* __restrict__ offsets, int* __restrict__ csr) {
    __shared__ int hist[256];
    __shared__ int sc[256];
    __shared__ int cur[256];
    int b = blockIdx.x;
    int t = threadIdx.x;
    if (t < 256) hist[t] = 0;
    __syncthreads();
    int gbase = scanned[b * NBLK];
    int gend  = (b < NBUCK - 1) ? scanned[(b + 1) * NBLK] : NE;
    int count = gend - gbase;
    const unsigned int* bd = bucketed + gbase;
    for (int e = t; e < count; e += 512) atomicAdd(&hist[bd[e] >> 16], 1);
    __syncthreads();
    if (t < 256) sc[t] = hist[t];
    __syncthreads();
    for (int off = 1; off < 256; off <<= 1) {
        int a = 0;
        if (t < 256 && t >= off) a = sc[t - off];
        __syncthreads();
        if (t < 256) sc[t] += a;
        __syncthreads();
    }
    if (t < 256) {
        int excl = sc[t] - hist[t];
        cur[t] = excl;
        int node = b * 256 + t;
        if (node < NN) offsets[node] = gbase + excl;
    }
    if (b == NBUCK - 1 && t == 0) offsets[NN] = NE;
    __syncthreads();
    for (int e = t; e < count; e += 512) {
        unsigned int v = bd[e];
        int p = atomicAdd(&cur[v >> 16], 1);
        csr[gbase + p] = (int)(v & 0xFFFFu);
    }
}

// ---------- H = X @ W -> bf16 : 512 thr = 2 row-halves x 4 col-quarters ----------
// wave-uniform wq = t>>7 keeps W loads on the scalar path (R8 lesson: per-WAVE uniformity)
__global__ __launch_bounds__(512) void gemm64_kernel(const float* __restrict__ X,
                                                     const float* __restrict__ W,
                                                     __hip_bfloat16* __restrict__ H,
                                                     int nrows) {
    __shared__ float Xl[128 * 65];   // +1 pad
    int t = threadIdx.x;
    int base = blockIdx.x * 128;
    for (int idx = t; idx < 128 * 16; idx += 512) {
        int row = idx >> 4;
        int c4  = idx & 15;
        float4 v = make_float4(0.f, 0.f, 0.f, 0.f);
        if (base + row < nrows)
            v = *reinterpret_cast<const float4*>(&X[(size_t)(base + row) * 64 + c4 * 4]);
        float* p = &Xl[row * 65 + c4 * 4];
        p[0] = v.x; p[1] = v.y; p[2] = v.z; p[3] = v.w;
    }
    __syncthreads();
    int r  = t & 127;     // local row
    int wq = t >> 7;      // col-quarter 0..3 — constant within each 64-lane wave
    float acc[16];
#pragma unroll
    for (int c = 0; c < 16; ++c) acc[c] = 0.f;
#pragma unroll 4
    for (int k = 0; k < 64; ++k) {
        float xv = Xl[r * 65 + k];
#pragma unroll
        for (int c4 = 0; c4 < 4; ++c4) {
            float4 w = *reinterpret_cast<const float4*>(&W[k * 64 + wq * 16 + c4 * 4]); // s_load
            acc[c4 * 4 + 0] = fmaf(xv, w.x, acc[c4 * 4 + 0]);
            acc[c4 * 4 + 1] = fmaf(xv, w.y, acc[c4 * 4 + 1]);
            acc[c4 * 4 + 2] = fmaf(xv, w.z, acc[c4 * 4 + 2]);
            acc[c4 * 4 + 3] = fmaf(xv, w.w, acc[c4 * 4 + 3]);
        }
    }
    int row = base + r;
    if (row < nrows) {
        alignas(16) __hip_bfloat16 hb[16];
#pragma unroll
        for (int c = 0; c < 16; ++c) hb[c] = __float2bfloat16(acc[c]);
        uint4* dst4 = reinterpret_cast<uint4*>(&H[(size_t)row * 64 + wq * 16]);
        const uint4* src4 = reinterpret_cast<const uint4*>(hb);
        dst4[0] = src4[0];
        dst4[1] = src4[1];
    }
}

// ---------- per-node CSR gather (bf16 H, 8-deep MLP) + ReLU + batched add-pool ----------
template <bool WRITE_X>
__global__ void gather_kernel(const __hip_bfloat16* __restrict__ H,
                              const int* __restrict__ offsets,
                              const int* __restrict__ csr, const int* __restrict__ batch,
                              float* __restrict__ Xout, float* __restrict__ pool) {
    int tid = blockIdx.x * blockDim.x + threadIdx.x;
    int lane = tid & 63;
    int gw = tid >> 6;
    int nw = (gridDim.x * blockDim.x) >> 6;
    int chunk = (NN + nw - 1) / nw;           // contiguous nodes per wave
    int start = gw * chunk;
    if (start >= NN) return;
    int stop = min(start + chunk, NN);
    float pacc = 0.f;
    int curg = batch[start];
    for (int n = start; n < stop; ++n) {
        int beg = offsets[n], end = offsets[n + 1];
        float a0 = 0.f, a1 = 0.f, a2 = 0.f, a3 = 0.f;
        float a4 = 0.f, a5 = 0.f, a6 = 0.f, a7 = 0.f;
        int i = beg;
        for (; i + 8 <= end; i += 8) {        // 8 independent loads in flight
            int s0 = csr[i],     s1 = csr[i + 1], s2 = csr[i + 2], s3 = csr[i + 3];
            int s4 = csr[i + 4], s5 = csr[i + 5], s6 = csr[i + 6], s7 = csr[i + 7];
            a0 += __bfloat162float(H[(size_t)s0 * 64 + lane]);
            a1 += __bfloat162float(H[(size_t)s1 * 64 + lane]);
            a2 += __bfloat162float(H[(size_t)s2 * 64 + lane]);
            a3 += __bfloat162float(H[(size_t)s3 * 64 + lane]);
            a4 += __bfloat162float(H[(size_t)s4 * 64 + lane]);
            a5 += __bfloat162float(H[(size_t)s5 * 64 + lane]);
            a6 += __bfloat162float(H[(size_t)s6 * 64 + lane]);
            a7 += __bfloat162float(H[(size_t)s7 * 64 + lane]);
        }
        if (i + 4 <= end) {
            int s0 = csr[i], s1 = csr[i + 1], s2 = csr[i + 2], s3 = csr[i + 3];
            a0 += __bfloat162float(H[(size_t)s0 * 64 + lane]);
            a1 += __bfloat162float(H[(size_t)s1 * 64 + lane]);
            a2 += __bfloat162float(H[(size_t)s2 * 64 + lane]);
            a3 += __bfloat162float(H[(size_t)s3 * 64 + lane]);
            i += 4;
        }
        for (; i < end; ++i) a0 += __bfloat162float(H[(size_t)csr[i] * 64 + lane]);
        float v = fmaxf(((a0 + a1) + (a2 + a3)) + ((a4 + a5) + (a6 + a7)), 0.f);
        if (WRITE_X) Xout[(size_t)n * 64 + lane] = v;
        int g = batch[n];
        if (g != curg) {                       // wave-uniform (batch sorted)
            unsafeAtomicAdd(&pool[(size_t)curg * 64 + lane], pacc);
            pacc = 0.f; curg = g;
        }
        pacc += v;
    }
    unsafeAtomicAdd(&pool[(size_t)curg * 64 + lane], pacc);
}

// ---------- out[g] = relu(sum_l pool_l[g] @ Wp_l) ----------
__global__ void final_kernel(const float* __restrict__ P1, const float* __restrict__ P2,
                             const float* __restrict__ P3,
                             const float* __restrict__ Wp1, const float* __restrict__ Wp2,
                             const float* __restrict__ Wp3, float* __restrict__ out) {
    int g = blockIdx.x;
    int c = threadIdx.x;  // 64
    float acc = 0.f;
#pragma unroll
    for (int k = 0; k < 64; ++k) {
        acc = fmaf(P1[g * 64 + k], Wp1[k * 64 + c], acc);
        acc = fmaf(P2[g * 64 + k], Wp2[k * 64 + c], acc);
        acc = fmaf(P3[g * 64 + k], Wp3[k * 64 + c], acc);
    }
    out[g * 64 + c] = fmaxf(acc, 0.f);
}

extern "C" void kernel_launch(void* const* d_in, const int* in_sizes, int n_in,
                              void* d_out, int out_size, void* d_ws, size_t ws_size,
                              hipStream_t stream) {
    const float* x     = (const float*)d_in[0];
    const int*   eidx  = (const int*)d_in[1];   // [2, NE]
    const int*   batch = (const int*)d_in[2];   // [NN], sorted
    const float* W1  = (const float*)d_in[3];
    const float* W2  = (const float*)d_in[4];
    const float* W3  = (const float*)d_in[5];
    const float* Wp1 = (const float*)d_in[6];
    const float* Wp2 = (const float*)d_in[7];
    const float* Wp3 = (const float*)d_in[8];
    float* out = (float*)d_out;

    const int* src = eidx;
    const int* dst = eidx + NE;

    // ---- workspace layout (~28 MB) ----
    __hip_bfloat16* bufH = (__hip_bfloat16*)d_ws;        // H bf16 (6.4 MB)
    float* bufX  = (float*)(bufH + (size_t)NN * DIM);    // x_l fp32 (12.8 MB)
    float* pool1 = bufX + (size_t)NN * DIM;              // 3 x 64 KB
    float* pool2 = pool1 + (size_t)NG * DIM;
    float* pool3 = pool2 + (size_t)NG * DIM;
    int* hist     = (int*)(pool3 + (size_t)NG * DIM);    // TOT2D
    int* scanned  = hist + TOT2D;                        // TOT2D
    int* blocksum = scanned + TOT2D;                     // 64
    int* offsets  = blocksum + 64;                       // NN+1
    unsigned int* bucketed = (unsigned int*)(offsets + NN + 1);  // NE (4 MB)
    int* csr      = (int*)(bucketed + NE);               // NE (4 MB)

    // ---- build exact CSR: hist(+pool zero) -> scan -> permute -> bucket sort ----
    hist2d_kernel<<<NBLK, 512, 0, stream>>>(dst, hist, pool1);
    scanA_kernel<<<SCANB, 1024, 0, stream>>>(hist, blocksum);
    scanB_kernel<<<1, 64, 0, stream>>>(blocksum);
    scanC_kernel<<<SCANB, 1024, 0, stream>>>(hist, blocksum, scanned);
    permute_kernel<<<NBLK, 512, 0, stream>>>(src, dst, scanned, bucketed);
    bucket_sort_kernel<<<NBUCK, 512, 0, stream>>>(bucketed, scanned, offsets, csr);

    const int gemm_blocks = (NN + 127) / 128;           // 391 blocks x 512 thr
    const int gath_blocks = 1792;                        // 7168 waves, 7 nodes each

    // layer 1
    gemm64_kernel<<<gemm_blocks, 512, 0, stream>>>(x, W1, bufH, NN);
    gather_kernel<true><<<gath_blocks, 256, 0, stream>>>(bufH, offsets, csr, batch, bufX, pool1);
    // layer 2
    gemm64_kernel<<<gemm_blocks, 512, 0, stream>>>(bufX, W2, bufH, NN);
    gather_kernel<true><<<gath_blocks, 256, 0, stream>>>(bufH, offsets, csr, batch, bufX, pool2);
    // layer 3 (x3 only feeds the pool -> skip Xout write)
    gemm64_kernel<<<gemm_blocks, 512, 0, stream>>>(bufX, W3, bufH, NN);
    gather_kernel<false><<<gath_blocks, 256, 0, stream>>>(bufH, offsets, csr, batch, nullptr, pool3);

    final_kernel<<<NG, 64, 0, stream>>>(pool1, pool2, pool3, Wp1, Wp2, Wp3, out);
}

// Round 17
// 295.029 us; speedup vs baseline: 1.0482x; 1.0434x over previous
//
#include <hip/hip_runtime.h>
#include <hip/hip_bf16.h>

#define NN 50000
#define NE 1000000
#define DIM 64
#define NG 256
#define NBUCK 196        // ceil(NN/256) buckets of 256 dst nodes
#define ROUND 4096       // edges per block in hist2d/permute
#define NBLK 245         // ceil(NE/ROUND)
#define TOT2D (NBUCK * NBLK)   // 48020
#define SCANB 47         // ceil(TOT2D/1024)

// ---- pass 1: per-block bucket histogram -> hist[b*NBLK + blk]; also zeros pool ----
__global__ __launch_bounds__(512) void hist2d_kernel(const int* __restrict__ dst,
                                                     int* __restrict__ hist,
                                                     float* __restrict__ pool) {
    int gtid = blockIdx.x * 512 + threadIdx.x;
    for (int i = gtid; i < 3 * NG * DIM; i += NBLK * 512) pool[i] = 0.f;

    __shared__ int h[NBUCK];
    int t = threadIdx.x;
    if (t < NBUCK) h[t] = 0;
    __syncthreads();
    int base = blockIdx.x * ROUND;
#pragma unroll
    for (int it = 0; it < 8; ++it) {
        int e = base + it * 512 + t;
        if (e < NE) atomicAdd(&h[dst[e] >> 8], 1);
    }
    __syncthreads();
    if (t < NBUCK) hist[t * NBLK + blockIdx.x] = h[t];
}

// ---- pass 2a: per-1024-chunk sums ----
__global__ __launch_bounds__(1024) void scanA_kernel(const int* __restrict__ hist,
                                                     int* __restrict__ blocksum) {
    __shared__ int tmp[1024];
    int t = threadIdx.x;
    int i = blockIdx.x * 1024 + t;
    tmp[t] = (i < TOT2D) ? hist[i] : 0;
    __syncthreads();
    for (int s = 512; s > 0; s >>= 1) {
        if (t < s) tmp[t] += tmp[t + s];
        __syncthreads();
    }
    if (t == 0) blocksum[blockIdx.x] = tmp[0];
}

// ---- pass 2b: chunk scan; each block redundantly scans the 47 raw block sums
//      (folds old scanB) — BARRIER-SYNCED (R15 lesson: no barrier-free LDS scans) ----
__global__ __launch_bounds__(1024) void scanC_kernel(const int* __restrict__ hist,
                                                     const int* __restrict__ blocksum,
                                                     int* __restrict__ scanned) {
    __shared__ int tmp[1024];
    __shared__ int bs[64];
    int t = threadIdx.x;
    if (t < 64) bs[t] = (t < SCANB) ? blocksum[t] : 0;
    __syncthreads();
#pragma unroll
    for (int off = 1; off < 64; off <<= 1) {
        int a = 0;
        if (t < 64 && t >= off) a = bs[t - off];
        __syncthreads();
        if (t < 64) bs[t] += a;
        __syncthreads();
    }
    int base = (blockIdx.x == 0) ? 0 : bs[blockIdx.x - 1];   // exclusive prefix
    int i = blockIdx.x * 1024 + t;
    int v = (i < TOT2D) ? hist[i] : 0;
    tmp[t] = v;
    __syncthreads();
    for (int off = 1; off < 1024; off <<= 1) {
        int a = (t >= off) ? tmp[t - off] : 0;
        __syncthreads();
        tmp[t] += a;
        __syncthreads();
    }
    if (i < TOT2D) scanned[i] = tmp[t] - v + base;
}

// ---- pass 3: permute edges into bucket-major order (no global atomics) ----
__global__ __launch_bounds__(512) void permute_kernel(
    const int* __restrict__ src, const int* __restrict__ dst,
    const int* __restrict__ scanned, unsigned int* __restrict__ bucketed) {
    __shared__ int cur[NBUCK];
    int t = threadIdx.x;
    int blk = blockIdx.x;
    if (t < NBUCK) cur[t] = scanned[t * NBLK + blk];
    __syncthreads();
    int base = blk * ROUND;
#pragma unroll
    for (int it = 0; it < 8; ++it) {
        int e = base + it * 512 + t;
        if (e < NE) {
            int d = dst[e];
            int s = src[e];
            int b = d >> 8;
            int pos = atomicAdd(&cur[b], 1);
            bucketed[pos] = ((unsigned int)(d & 255) << 16) | (unsigned int)s;
        }
    }
}

// ---- pass 4: per-bucket counting sort -> exact CSR ----
__global__ __launch_bounds__(512) void bucket_sort_kernel(
    const unsigned int* __restrict__ bucketed, const int* __restrict__ scanned,
    int* __restrict__ offsets, int* __restrict__ csr) {
    __shared__ int hist[256];
    __shared__ int sc[256];
    __shared__ int cur[256];
    int b = blockIdx.x;
    int t = threadIdx.x;
    if (t < 256) hist[t] = 0;
    __syncthreads();
    int gbase = scanned[b * NBLK];
    int gend  = (b < NBUCK - 1) ? scanned[(b + 1) * NBLK] : NE;
    int count = gend - gbase;
    const unsigned int* bd = bucketed + gbase;
    for (int e = t; e < count; e += 512) atomicAdd(&hist[bd[e] >> 16], 1);
    __syncthreads();
    if (t < 256) sc[t] = hist[t];
    __syncthreads();
    for (int off = 1; off < 256; off <<= 1) {
        int a = 0;
        if (t < 256 && t >= off) a = sc[t - off];
        __syncthreads();
        if (t < 256) sc[t] += a;
        __syncthreads();
    }
    if (t < 256) {
        int excl = sc[t] - hist[t];
        cur[t] = excl;
        int node = b * 256 + t;
        if (node < NN) offsets[node] = gbase + excl;
    }
    if (b == NBUCK - 1 && t == 0) offsets[NN] = NE;
    __syncthreads();
    for (int e = t; e < count; e += 512) {
        unsigned int v = bd[e];
        int p = atomicAdd(&cur[v >> 16], 1);
        csr[gbase + p] = (int)(v & 0xFFFFu);
    }
}

// ---------- H = X @ W -> bf16 : thread-per-row, W wave-uniform (s_load) — R11-proven ----------
__global__ __launch_bounds__(128) void gemm64_kernel(const float* __restrict__ X,
                                                     const float* __restrict__ W,
                                                     __hip_bfloat16* __restrict__ H,
                                                     int nrows) {
    __shared__ float Xl[128 * 65];   // +1 pad
    int t = threadIdx.x;
    int base = blockIdx.x * 128;
    for (int idx = t; idx < 128 * 16; idx += 128) {
        int row = idx >> 4;
        int c4  = idx & 15;
        float4 v = make_float4(0.f, 0.f, 0.f, 0.f);
        if (base + row < nrows)
            v = *reinterpret_cast<const float4*>(&X[(size_t)(base + row) * 64 + c4 * 4]);
        float* p = &Xl[row * 65 + c4 * 4];
        p[0] = v.x; p[1] = v.y; p[2] = v.z; p[3] = v.w;
    }
    __syncthreads();
    float acc[64];
#pragma unroll
    for (int c = 0; c < 64; ++c) acc[c] = 0.f;
#pragma unroll 4
    for (int k = 0; k < 64; ++k) {
        float xv = Xl[t * 65 + k];
#pragma unroll
        for (int c4 = 0; c4 < 16; ++c4) {
            float4 w = *reinterpret_cast<const float4*>(&W[k * 64 + c4 * 4]); // uniform -> s_load
            acc[c4 * 4 + 0] = fmaf(xv, w.x, acc[c4 * 4 + 0]);
            acc[c4 * 4 + 1] = fmaf(xv, w.y, acc[c4 * 4 + 1]);
            acc[c4 * 4 + 2] = fmaf(xv, w.z, acc[c4 * 4 + 2]);
            acc[c4 * 4 + 3] = fmaf(xv, w.w, acc[c4 * 4 + 3]);
        }
    }
    int row = base + t;
    if (row < nrows) {
        alignas(16) __hip_bfloat16 hb[64];
#pragma unroll
        for (int c = 0; c < 64; ++c) hb[c] = __float2bfloat16(acc[c]);
        uint4* dst4 = reinterpret_cast<uint4*>(&H[(size_t)row * 64]);
        const uint4* src4 = reinterpret_cast<const uint4*>(hb);
#pragma unroll
        for (int q = 0; q < 8; ++q) dst4[q] = src4[q];
    }
}

// ---------- per-node CSR gather (bf16 H, 8-deep MLP) + ReLU + batched add-pool ----------
template <bool WRITE_X>
__global__ void gather_kernel(const __hip_bfloat16* __restrict__ H,
                              const int* __restrict__ offsets,
                              const int* __restrict__ csr, const int* __restrict__ batch,
                              float* __restrict__ Xout, float* __restrict__ pool) {
    int tid = blockIdx.x * blockDim.x + threadIdx.x;
    int lane = tid & 63;
    int gw = tid >> 6;
    int nw = (gridDim.x * blockDim.x) >> 6;
    int chunk = (NN + nw - 1) / nw;           // contiguous nodes per wave
    int start = gw * chunk;
    if (start >= NN) return;
    int stop = min(start + chunk, NN);
    float pacc = 0.f;
    int curg = batch[start];
    for (int n = start; n < stop; ++n) {
        int beg = offsets[n], end = offsets[n + 1];
        float a0 = 0.f, a1 = 0.f, a2 = 0.f, a3 = 0.f;
        float a4 = 0.f, a5 = 0.f, a6 = 0.f, a7 = 0.f;
        int i = beg;
        for (; i + 8 <= end; i += 8) {        // 8 independent loads in flight
            int s0 = csr[i],     s1 = csr[i + 1], s2 = csr[i + 2], s3 = csr[i + 3];
            int s4 = csr[i + 4], s5 = csr[i + 5], s6 = csr[i + 6], s7 = csr[i + 7];
            a0 += __bfloat162float(H[(size_t)s0 * 64 + lane]);
            a1 += __bfloat162float(H[(size_t)s1 * 64 + lane]);
            a2 += __bfloat162float(H[(size_t)s2 * 64 + lane]);
            a3 += __bfloat162float(H[(size_t)s3 * 64 + lane]);
            a4 += __bfloat162float(H[(size_t)s4 * 64 + lane]);
            a5 += __bfloat162float(H[(size_t)s5 * 64 + lane]);
            a6 += __bfloat162float(H[(size_t)s6 * 64 + lane]);
            a7 += __bfloat162float(H[(size_t)s7 * 64 + lane]);
        }
        if (i + 4 <= end) {
            int s0 = csr[i], s1 = csr[i + 1], s2 = csr[i + 2], s3 = csr[i + 3];
            a0 += __bfloat162float(H[(size_t)s0 * 64 + lane]);
            a1 += __bfloat162float(H[(size_t)s1 * 64 + lane]);
            a2 += __bfloat162float(H[(size_t)s2 * 64 + lane]);
            a3 += __bfloat162float(H[(size_t)s3 * 64 + lane]);
            i += 4;
        }
        for (; i < end; ++i) a0 += __bfloat162float(H[(size_t)csr[i] * 64 + lane]);
        float v = fmaxf(((a0 + a1) + (a2 + a3)) + ((a4 + a5) + (a6 + a7)), 0.f);
        if (WRITE_X) Xout[(size_t)n * 64 + lane] = v;
        int g = batch[n];
        if (g != curg) {                       // wave-uniform (batch sorted)
            unsafeAtomicAdd(&pool[(size_t)curg * 64 + lane], pacc);
            pacc = 0.f; curg = g;
        }
        pacc += v;
    }
    unsafeAtomicAdd(&pool[(size_t)curg * 64 + lane], pacc);
}

// ---------- out[g] = relu(sum_l pool_l[g] @ Wp_l) ----------
__global__ void final_kernel(const float* __restrict__ P1, const float* __restrict__ P2,
                             const float* __restrict__ P3,
                             const float* __restrict__ Wp1, const float* __restrict__ Wp2,
                             const float* __restrict__ Wp3, float* __restrict__ out) {
    int g = blockIdx.x;
    int c = threadIdx.x;  // 64
    float acc = 0.f;
#pragma unroll
    for (int k = 0; k < 64; ++k) {
        acc = fmaf(P1[g * 64 + k], Wp1[k * 64 + c], acc);
        acc = fmaf(P2[g * 64 + k], Wp2[k * 64 + c], acc);
        acc = fmaf(P3[g * 64 + k], Wp3[k * 64 + c], acc);
    }
    out[g * 64 + c] = fmaxf(acc, 0.f);
}

extern "C" void kernel_launch(void* const* d_in, const int* in_sizes, int n_in,
                              void* d_out, int out_size, void* d_ws, size_t ws_size,
                              hipStream_t stream) {
    const float* x     = (const float*)d_in[0];
    const int*   eidx  = (const int*)d_in[1];   // [2, NE]
    const int*   batch = (const int*)d_in[2];   // [NN], sorted
    const float* W1  = (const float*)d_in[3];
    const float* W2  = (const float*)d_in[4];
    const float* W3  = (const float*)d_in[5];
    const float* Wp1 = (const float*)d_in[6];
    const float* Wp2 = (const float*)d_in[7];
    const float* Wp3 = (const float*)d_in[8];
    float* out = (float*)d_out;

    const int* src = eidx;
    const int* dst = eidx + NE;

    // ---- workspace layout (~28 MB) ----
    __hip_bfloat16* bufH = (__hip_bfloat16*)d_ws;        // H bf16 (6.4 MB)
    float* bufX  = (float*)(bufH + (size_t)NN * DIM);    // x_l fp32 (12.8 MB)
    float* pool1 = bufX + (size_t)NN * DIM;              // 3 x 64 KB
    float* pool2 = pool1 + (size_t)NG * DIM;
    float* pool3 = pool2 + (size_t)NG * DIM;
    int* hist     = (int*)(pool3 + (size_t)NG * DIM);    // TOT2D
    int* scanned  = hist + TOT2D;                        // TOT2D
    int* blocksum = scanned + TOT2D;                     // 64
    int* offsets  = blocksum + 64;                       // NN+1
    unsigned int* bucketed = (unsigned int*)(offsets + NN + 1);  // NE (4 MB)
    int* csr      = (int*)(bucketed + NE);               // NE (4 MB)

    // ---- build exact CSR: hist(+pool zero) -> scanA -> scanC(folded B, barrier-synced) ----
    hist2d_kernel<<<NBLK, 512, 0, stream>>>(dst, hist, pool1);
    scanA_kernel<<<SCANB, 1024, 0, stream>>>(hist, blocksum);
    scanC_kernel<<<SCANB, 1024, 0, stream>>>(hist, blocksum, scanned);
    permute_kernel<<<NBLK, 512, 0, stream>>>(src, dst, scanned, bucketed);
    bucket_sort_kernel<<<NBUCK, 512, 0, stream>>>(bucketed, scanned, offsets, csr);

    const int gemm_blocks = (NN + 127) / 128;           // 391
    const int gath_blocks = 1792;                        // 7168 waves, 7 nodes each

    // layer 1
    gemm64_kernel<<<gemm_blocks, 128, 0, stream>>>(x, W1, bufH, NN);
    gather_kernel<true><<<gath_blocks, 256, 0, stream>>>(bufH, offsets, csr, batch, bufX, pool1);
    // layer 2
    gemm64_kernel<<<gemm_blocks, 128, 0, stream>>>(bufX, W2, bufH, NN);
    gather_kernel<true><<<gath_blocks, 256, 0, stream>>>(bufH, offsets, csr, batch, bufX, pool2);
    // layer 3 (x3 only feeds the pool -> skip Xout write)
    gemm64_kernel<<<gemm_blocks, 128, 0, stream>>>(bufX, W3, bufH, NN);
    gather_kernel<false><<<gath_blocks, 256, 0, stream>>>(bufH, offsets, csr, batch, nullptr, pool3);

    final_kernel<<<NG, 64, 0, stream>>>(pool1, pool2, pool3, Wp1, Wp2, Wp3, out);
}